// Round 14
// baseline (1830.362 us; speedup 1.0000x reference)
//
#include <hip/hip_runtime.h>
#include <math.h>

typedef __attribute__((ext_vector_type(8))) short short8;
typedef __attribute__((ext_vector_type(4))) float f32x4;
typedef __attribute__((ext_vector_type(4))) float f4;
typedef __attribute__((ext_vector_type(4))) unsigned short us4;
typedef unsigned short u16;

#define Bn 32
#define Ln 128
#define Dn 512
#define LATn 256
#define Vn 50257
#define VPAD 50304
#define DFn 2048
#define Hn 8
#define HDn 64

#define GLD(src, dst) __builtin_amdgcn_global_load_lds( \
    (const __attribute__((address_space(1))) unsigned int*)(src), \
    (__attribute__((address_space(3))) unsigned int*)(dst), 16, 0, 0)

__device__ __forceinline__ u16 f2bf(float f) {
  union { float f; unsigned u; } v; v.f = f;
  unsigned r = 0x7FFFu + ((v.u >> 16) & 1u);
  return (u16)((v.u + r) >> 16);
}
__device__ __forceinline__ float bf2f(u16 u) {
  union { unsigned u; float f; } v; v.u = ((unsigned)u) << 16;
  return v.f;
}

// ---------------- all weights f32 -> bf16, one kernel (contiguous dst arena) -
__global__ __launch_bounds__(256)
void k_cvt_all(const float* __restrict__ s0, const float* __restrict__ s1,
               const float* __restrict__ s2, const float* __restrict__ s3,
               const float* __restrict__ s4, us4* __restrict__ dst) {
  const int C0 = 786432;    // qkv  4*1536*512/4
  const int C1 = 1048576;   // +out 4*512*512/4
  const int C2 = 2097152;   // +ff1 4*2048*512/4
  const int C3 = 3145728;   // +ff2
  const int C4 = 9584640;   // +op (VPAD*512/4)
  const int OPN4 = 6432896; // op real Vn*512/4
  int i = blockIdx.x * blockDim.x + threadIdx.x;
  int stride = gridDim.x * blockDim.x;
  for (; i < C4; i += stride) {
    const f4* src; int off; bool valid = true;
    if (i < C0)      { src = (const f4*)s0; off = i; }
    else if (i < C1) { src = (const f4*)s1; off = i - C0; }
    else if (i < C2) { src = (const f4*)s2; off = i - C1; }
    else if (i < C3) { src = (const f4*)s3; off = i - C2; }
    else             { src = (const f4*)s4; off = i - C3; valid = off < OPN4; }
    us4 o;
    if (valid) {
      f4 v = src[off];
      o[0] = f2bf(v[0]); o[1] = f2bf(v[1]); o[2] = f2bf(v[2]); o[3] = f2bf(v[3]);
    } else { o[0] = 0; o[1] = 0; o[2] = 0; o[3] = 0; }
    dst[i] = o;
  }
}

// ------------- cross-attention precompute, latent_proj fused in --------------
// (Lk=1 => softmax==1 => o = v).  Each block (i,b) recomputes mem[b] (cheap).
__global__ __launch_bounds__(256)
void k_ca(const float* __restrict__ z, const float* __restrict__ lp_w,
          const float* __restrict__ lp_b, const float* __restrict__ lp_g,
          const float* __restrict__ lp_be,
          const float* __restrict__ ca_qkv_w, const float* __restrict__ ca_qkv_b,
          const float* __restrict__ ca_out_w, const float* __restrict__ ca_out_b,
          float* __restrict__ ca_add) {
  int blk = blockIdx.x;
  int i = blk >> 5, b = blk & 31, t = threadIdx.x;
  __shared__ float zs[LATn];
  __shared__ float red[16];
  __shared__ float ms[Dn];
  __shared__ float vs[Dn];
  zs[t] = z[b * LATn + t];
  __syncthreads();
  // latent_proj: h = GELU(z @ lp_w.T + lp_b), ms = LN(h)
  float h[2];
  #pragma unroll
  for (int j = 0; j < 2; j++) {
    int oj = t + j * 256;
    const float* w = lp_w + (size_t)oj * LATn;
    float s0 = 0, s1 = 0, s2 = 0, s3 = 0;
    for (int k = 0; k < LATn; k += 4) {
      s0 += zs[k] * w[k]; s1 += zs[k+1] * w[k+1];
      s2 += zs[k+2] * w[k+2]; s3 += zs[k+3] * w[k+3];
    }
    float x = s0 + s1 + s2 + s3 + lp_b[oj];
    h[j] = 0.5f * x * (1.0f + erff(x * 0.70710678118654752f));
  }
  float sum = h[0] + h[1], sq = h[0]*h[0] + h[1]*h[1];
  for (int off = 32; off; off >>= 1) {
    sum += __shfl_down(sum, off, 64);
    sq  += __shfl_down(sq,  off, 64);
  }
  int lane = t & 63, wid = t >> 6;
  if (!lane) { red[wid] = sum; red[8 + wid] = sq; }
  __syncthreads();
  float ts = red[0] + red[1] + red[2] + red[3];
  float tq = red[8] + red[9] + red[10] + red[11];
  float mu = ts * (1.0f / Dn);
  float var = tq * (1.0f / Dn) - mu * mu;
  float rstd = rsqrtf(fmaxf(var, 0.0f) + 1e-5f);
  #pragma unroll
  for (int j = 0; j < 2; j++) {
    int oj = t + j * 256;
    ms[oj] = (h[j] - mu) * rstd * lp_g[oj] + lp_be[oj];
  }
  __syncthreads();
  // v = ms @ Wv_i.T + bv_i
  const float* wv = ca_qkv_w + ((size_t)i * 1536 + 1024) * Dn;
  const float* bv = ca_qkv_b + i * 1536 + 1024;
  for (int j = t; j < Dn; j += 256) {
    const float* w = wv + (size_t)j * Dn;
    float s0 = 0, s1 = 0, s2 = 0, s3 = 0;
    for (int k = 0; k < Dn; k += 4) {
      s0 += ms[k]*w[k]; s1 += ms[k+1]*w[k+1]; s2 += ms[k+2]*w[k+2]; s3 += ms[k+3]*w[k+3];
    }
    vs[j] = s0 + s1 + s2 + s3 + bv[j];
  }
  __syncthreads();
  // ca_add = v @ Wo_i.T + bo_i
  const float* wo = ca_out_w + (size_t)i * Dn * Dn;
  const float* bo = ca_out_b + i * Dn;
  for (int j = t; j < Dn; j += 256) {
    const float* w = wo + (size_t)j * Dn;
    float s0 = 0, s1 = 0, s2 = 0, s3 = 0;
    for (int k = 0; k < Dn; k += 4) {
      s0 += vs[k]*w[k]; s1 += vs[k+1]*w[k+1]; s2 += vs[k+2]*w[k+2]; s3 += vs[k+3]*w[k+3];
    }
    ca_add[((size_t)i * Bn + b) * Dn + j] = s0 + s1 + s2 + s3 + bo[j];
  }
}

// ---------------- embedding: Xb = bf16(tok_emb[ids] + pos_emb) ---------------
__global__ __launch_bounds__(128)
void k_embed(const int* __restrict__ ids, const float* __restrict__ tok,
             const float* __restrict__ pos, u16* __restrict__ Xb) {
  int r = blockIdx.x;
  int l = r & (Ln - 1);
  int id = ids[r];
  int c = threadIdx.x * 4;
  f4 te = *(const f4*)&tok[(size_t)id * Dn + c];
  f4 pe = *(const f4*)&pos[(size_t)l * Dn + c];
  f4 v = te + pe;
  us4 o = { f2bf(v[0]), f2bf(v[1]), f2bf(v[2]), f2bf(v[3]) };
  *(us4*)&Xb[(size_t)r * Dn + c] = o;
}

// ---------------- fused residual add + LayerNorm (bf16 residual stream) ------
__global__ __launch_bounds__(128)
void k_add_ln(u16* __restrict__ Xb, const u16* __restrict__ Y,
              const float* __restrict__ g, const float* __restrict__ be) {
  int r = blockIdx.x, t = threadIdx.x;
  int c = t * 4;
  us4 xb = *(const us4*)&Xb[(size_t)r * Dn + c];
  us4 yb = *(const us4*)&Y[(size_t)r * Dn + c];
  f4 v;
  v[0] = bf2f(xb[0]) + bf2f(yb[0]); v[1] = bf2f(xb[1]) + bf2f(yb[1]);
  v[2] = bf2f(xb[2]) + bf2f(yb[2]); v[3] = bf2f(xb[3]) + bf2f(yb[3]);
  float sum = v[0] + v[1] + v[2] + v[3];
  float sq = v[0]*v[0] + v[1]*v[1] + v[2]*v[2] + v[3]*v[3];
  for (int off = 32; off; off >>= 1) {
    sum += __shfl_down(sum, off, 64);
    sq  += __shfl_down(sq,  off, 64);
  }
  __shared__ float red[4];
  int lane = t & 63, w = t >> 6;
  if (!lane) { red[w] = sum; red[2 + w] = sq; }
  __syncthreads();
  sum = red[0] + red[1]; sq = red[2] + red[3];
  float mu = sum * (1.0f / Dn);
  float var = sq * (1.0f / Dn) - mu * mu;
  float rstd = rsqrtf(fmaxf(var, 0.0f) + 1e-5f);
  f4 gg = *(const f4*)&g[c];
  f4 bb = *(const f4*)&be[c];
  f4 o = (v - mu) * rstd * gg + bb;
  us4 ob = { f2bf(o[0]), f2bf(o[1]), f2bf(o[2]), f2bf(o[3]) };
  *(us4*)&Xb[(size_t)r * Dn + c] = ob;
}

// ---------------- fused LN1(X+Y) then LN2(. + CA), bf16 residual -------------
__global__ __launch_bounds__(128)
void k_add_ln12(u16* __restrict__ Xb, const u16* __restrict__ Y,
                const float* __restrict__ CA,
                const float* __restrict__ g1, const float* __restrict__ b1,
                const float* __restrict__ g2, const float* __restrict__ b2) {
  int r = blockIdx.x, t = threadIdx.x;
  int c = t * 4;
  __shared__ float red[8];
  int lane = t & 63, w = t >> 6;
  us4 xb = *(const us4*)&Xb[(size_t)r * Dn + c];
  us4 yb = *(const us4*)&Y[(size_t)r * Dn + c];
  f4 v;
  v[0] = bf2f(xb[0]) + bf2f(yb[0]); v[1] = bf2f(xb[1]) + bf2f(yb[1]);
  v[2] = bf2f(xb[2]) + bf2f(yb[2]); v[3] = bf2f(xb[3]) + bf2f(yb[3]);
  float sum = v[0] + v[1] + v[2] + v[3];
  float sq = v[0]*v[0] + v[1]*v[1] + v[2]*v[2] + v[3]*v[3];
  for (int off = 32; off; off >>= 1) {
    sum += __shfl_down(sum, off, 64);
    sq  += __shfl_down(sq,  off, 64);
  }
  if (!lane) { red[w] = sum; red[2 + w] = sq; }
  __syncthreads();
  sum = red[0] + red[1]; sq = red[2] + red[3];
  float mu = sum * (1.0f / Dn);
  float var = sq * (1.0f / Dn) - mu * mu;
  float rstd = rsqrtf(fmaxf(var, 0.0f) + 1e-5f);
  f4 g1v = *(const f4*)&g1[c];
  f4 b1v = *(const f4*)&b1[c];
  f4 o1 = (v - mu) * rstd * g1v + b1v;
  f4 ca = *(const f4*)&CA[(size_t)(r >> 7) * Dn + c];
  f4 v2 = o1 + ca;
  float sum2 = v2[0] + v2[1] + v2[2] + v2[3];
  float sq2 = v2[0]*v2[0] + v2[1]*v2[1] + v2[2]*v2[2] + v2[3]*v2[3];
  for (int off = 32; off; off >>= 1) {
    sum2 += __shfl_down(sum2, off, 64);
    sq2  += __shfl_down(sq2,  off, 64);
  }
  if (!lane) { red[4 + w] = sum2; red[6 + w] = sq2; }
  __syncthreads();
  sum2 = red[4] + red[5]; sq2 = red[6] + red[7];
  float mu2 = sum2 * (1.0f / Dn);
  float var2 = sq2 * (1.0f / Dn) - mu2 * mu2;
  float rstd2 = rsqrtf(fmaxf(var2, 0.0f) + 1e-5f);
  f4 g2v = *(const f4*)&g2[c];
  f4 b2v = *(const f4*)&b2[c];
  f4 o2 = (v2 - mu2) * rstd2 * g2v + b2v;
  us4 ob = { f2bf(o2[0]), f2bf(o2[1]), f2bf(o2[2]), f2bf(o2[3]) };
  *(us4*)&Xb[(size_t)r * Dn + c] = ob;
}

// ---------------- MFMA causal attention (R9-R13 passing kernel, unchanged) ---
__global__ __launch_bounds__(256, 1)
void k_attn_m(const u16* __restrict__ QKV, u16* __restrict__ Ob) {
  constexpr int QS = 0;
  constexpr int KS = 9216;
  constexpr int SFB = 36864;
  constexpr int VTB = 36864 + 66048;
  constexpr int MXB = VTB + 17408;
  constexpr int LXB = MXB + 1024;
  __shared__ __align__(16) char smem[LXB + 1024];
  u16* U = (u16*)smem;
  float* Sf = (float*)(smem + SFB);
  u16* Vt = (u16*)(smem + VTB);
  float* Mx = (float*)(smem + MXB);
  float* Lx = (float*)(smem + LXB);

  int bh = blockIdx.x, b = bh >> 3, h = bh & 7;
  int tid = threadIdx.x, lane = tid & 63, wid = tid >> 6;
  int r = tid & 127, half = tid >> 7;

  {
    const u16* qk = QKV + (size_t)(b * 128 + r) * 1536 + (half ? 512 : 0) + h * 64;
    u16* dst = U + (half ? KS : QS) + r * 72;
    #pragma unroll
    for (int i = 0; i < 64; i += 8)
      *(short8*)(dst + i) = *(const short8*)(qk + i);
    const u16* vsrc = QKV + (size_t)(b * 128 + r) * 1536 + 1024 + h * 64 + half * 32;
    #pragma unroll
    for (int i = 0; i < 32; i += 8) {
      short8 v = *(const short8*)(vsrc + i);
      #pragma unroll
      for (int j = 0; j < 8; j++)
        Vt[(half * 32 + i + j) * 136 + r] = (u16)v[j];
    }
  }
  __syncthreads();

  int qb = wid * 32;
  int fr = lane & 15, qk8 = (lane >> 4) * 8, qrl = (lane >> 4) * 4;
  f32x4 sacc[2][8] = {};
  #pragma unroll
  for (int s = 0; s < 2; s++) {
    short8 av[2], bv[8];
    #pragma unroll
    for (int mi = 0; mi < 2; mi++)
      av[mi] = *(const short8*)(U + QS + (qb + mi * 16 + fr) * 72 + s * 32 + qk8);
    #pragma unroll
    for (int nj = 0; nj < 8; nj++)
      bv[nj] = *(const short8*)(U + KS + (nj * 16 + fr) * 72 + s * 32 + qk8);
    #pragma unroll
    for (int mi = 0; mi < 2; mi++)
      #pragma unroll
      for (int nj = 0; nj < 8; nj++)
        sacc[mi][nj] = __builtin_amdgcn_mfma_f32_16x16x32_bf16(
            av[mi], bv[nj], sacc[mi][nj], 0, 0, 0);
  }
  #pragma unroll
  for (int mi = 0; mi < 2; mi++)
    #pragma unroll
    for (int nj = 0; nj < 8; nj++)
      #pragma unroll
      for (int g = 0; g < 4; g++) {
        int q = qb + mi * 16 + qrl + g;
        int k = nj * 16 + fr;
        Sf[q * 129 + k] = (k <= q) ? sacc[mi][nj][g] * 0.125f : -1e30f;
      }
  __syncthreads();

  int kr = half * 64;
  float m = -1e30f;
  for (int k = 0; k < 64; k++) m = fmaxf(m, Sf[r * 129 + kr + k]);
  Mx[half * 128 + r] = m;
  __syncthreads();
  float mm = fmaxf(Mx[r], Mx[128 + r]);
  float l = 0.0f;
  for (int k = 0; k < 64; k++) {
    float p = __expf(Sf[r * 129 + kr + k] - mm);
    Sf[r * 129 + kr + k] = p;
    l += p;
  }
  Lx[half * 128 + r] = l;
  __syncthreads();
  float linv = 1.0f / (Lx[r] + Lx[128 + r]);
  #pragma unroll
  for (int kc = 0; kc < 8; kc++) {
    short8 pv;
    #pragma unroll
    for (int j = 0; j < 8; j++)
      pv[j] = (short)f2bf(Sf[r * 129 + kr + kc * 8 + j] * linv);
    *(short8*)(U + r * 136 + kr + kc * 8) = pv;
  }
  __syncthreads();

  f32x4 oacc[2][4] = {};
  #pragma unroll
  for (int ks = 0; ks < 4; ks++) {
    short8 av[2], bv[4];
    #pragma unroll
    for (int mi = 0; mi < 2; mi++)
      av[mi] = *(const short8*)(U + (qb + mi * 16 + fr) * 136 + ks * 32 + qk8);
    #pragma unroll
    for (int nj = 0; nj < 4; nj++)
      bv[nj] = *(const short8*)(Vt + (nj * 16 + fr) * 136 + ks * 32 + qk8);
    #pragma unroll
    for (int mi = 0; mi < 2; mi++)
      #pragma unroll
      for (int nj = 0; nj < 4; nj++)
        oacc[mi][nj] = __builtin_amdgcn_mfma_f32_16x16x32_bf16(
            av[mi], bv[nj], oacc[mi][nj], 0, 0, 0);
  }
  #pragma unroll
  for (int mi = 0; mi < 2; mi++)
    #pragma unroll
    for (int nj = 0; nj < 4; nj++)
      #pragma unroll
      for (int g = 0; g < 4; g++) {
        int q = qb + mi * 16 + qrl + g;
        int d = nj * 16 + fr;
        Ob[(size_t)(b * 128 + q) * 512 + h * 64 + d] = f2bf(oacc[mi][nj][g]);
      }
}

// ---------------- layer GEMM (R8-R13 passing kernel, unchanged) --------------
template <int EPI, int BNT>
__global__ __launch_bounds__(256, (BNT == 128 ? 2 : 3))
void k_gemm_bt(const u16* __restrict__ A, const u16* __restrict__ Bw,
               const float* __restrict__ bias, void* __restrict__ Cout,
               int gm, int N, int K, int ldc) {
  constexpr int NREP = BNT / 32;
  constexpr int ASTRIDE = 128 * 64;
  constexpr int BSTRIDE = BNT * 64;
  constexpr int TSTRIDE = BNT + 4;
  constexpr int NLA = 4;
  constexpr int NLB = BNT / 32;
  __shared__ __align__(16) char smem[(ASTRIDE + BSTRIDE) * 4];
  u16* As = (u16*)smem;
  u16* Bs = (u16*)(smem + ASTRIDE * 4);
  float* Ts = (float*)smem;

  int lin = blockIdx.x;
  int bm = lin % gm, bn = lin / gm;
  int tid = threadIdx.x, lane = tid & 63, wid = tid >> 6;
  int wr = wid >> 1, wc = wid & 1;
  int fr = lane & 15, q = lane >> 4;
  f32x4 acc[4][NREP] = {};

  auto stage = [&](int it) {
    int buf = it & 1;
    #pragma unroll
    for (int l = 0; l < NLA; l++) {
      int c = tid + l * 256;
      int row = c >> 3;
      int kcg = (c & 7) ^ (row & 7);
      GLD(A + (size_t)(bm * 128 + row) * K + it * 64 + kcg * 8,
          (char*)(As + buf * ASTRIDE) + c * 16);
    }
    #pragma unroll
    for (int l = 0; l < NLB; l++) {
      int c = tid + l * 256;
      int row = c >> 3;
      int kcg = (c & 7) ^ (row & 7);
      GLD(Bw + (size_t)(bn * BNT + row) * K + it * 64 + kcg * 8,
          (char*)(Bs + buf * BSTRIDE) + c * 16);
    }
  };

  int nt = K >> 6;
  stage(0);
  for (int it = 0; it < nt; ++it) {
    int cur = it & 1;
    if (it + 1 < nt) {
      stage(it + 1);
      if constexpr (BNT == 128) asm volatile("s_waitcnt vmcnt(8)" ::: "memory");
      else                      asm volatile("s_waitcnt vmcnt(6)" ::: "memory");
    } else {
      asm volatile("s_waitcnt vmcnt(0)" ::: "memory");
    }
    __builtin_amdgcn_sched_barrier(0);
    __builtin_amdgcn_s_barrier();
    __builtin_amdgcn_sched_barrier(0);
    short8 av[2][4], bv[2][NREP];
    #pragma unroll
    for (int s = 0; s < 2; s++) {
      #pragma unroll
      for (int mi = 0; mi < 4; mi++) {
        int row = wr * 64 + mi * 16 + fr;
        int phys = (s * 4 + q) ^ (row & 7);
        av[s][mi] = *(const short8*)&As[cur * ASTRIDE + row * 64 + phys * 8];
      }
      #pragma unroll
      for (int nj = 0; nj < NREP; nj++) {
        int row = wc * (BNT / 2) + nj * 16 + fr;
        int phys = (s * 4 + q) ^ (row & 7);
        bv[s][nj] = *(const short8*)&Bs[cur * BSTRIDE + row * 64 + phys * 8];
      }
    }
    #pragma unroll
    for (int s = 0; s < 2; s++)
      #pragma unroll
      for (int mi = 0; mi < 4; mi++)
        #pragma unroll
        for (int nj = 0; nj < NREP; nj++)
          acc[mi][nj] = __builtin_amdgcn_mfma_f32_16x16x32_bf16(
              av[s][mi], bv[s][nj], acc[mi][nj], 0, 0, 0);
    asm volatile("s_waitcnt lgkmcnt(0)" ::: "memory");
    __builtin_amdgcn_sched_barrier(0);
    __builtin_amdgcn_s_barrier();
    __builtin_amdgcn_sched_barrier(0);
  }

  float bb[NREP];
  #pragma unroll
  for (int nj = 0; nj < NREP; nj++) {
    int cg = bn * BNT + wc * (BNT / 2) + nj * 16 + fr;
    bb[nj] = (cg < N) ? bias[cg] : 0.0f;
  }
  int rl0 = (lane >> 4) * 4;
  #pragma unroll
  for (int mi = 0; mi < 4; mi++) {
    #pragma unroll
    for (int nj = 0; nj < NREP; nj++) {
      int colL = wc * (BNT / 2) + nj * 16 + fr;
      #pragma unroll
      for (int r = 0; r < 4; r++)
        Ts[(wr * 16 + rl0 + r) * TSTRIDE + colL] = acc[mi][nj][r] + bb[nj];
    }
    __syncthreads();
    constexpr int ITERS = (32 * BNT) / 256;
    #pragma unroll
    for (int i = 0; i < ITERS; i++) {
      int flat = i * 256 + tid;
      int rowf = flat / BNT, col = flat % BNT;
      float v = Ts[rowf * TSTRIDE + col];
      int row_g = bm * 128 + (rowf >> 4) * 64 + mi * 16 + (rowf & 15);
      int col_g = bn * BNT + col;
      size_t off = (size_t)row_g * ldc + col_g;
      if (EPI == 0) {
        if (col_g < N) ((float*)Cout)[off] = v;
      } else if (EPI == 1) {
        ((u16*)Cout)[off] = f2bf(fmaxf(v, 0.0f));
      } else {
        ((u16*)Cout)[off] = f2bf(v);
      }
    }
    if (mi < 3) __syncthreads();
  }
}

// ---------------- vocab GEMM: 256x256 tile, BK=32, 8 waves, 2 blocks/CU ------
// Same proven 2-phase protocol (R4-R13); counts re-derived for BK=32:
// 4 GLDs/stage -> vmcnt(4).  LDS halved to 64 KB -> 2 blocks/CU (4 waves/SIMD)
// so independent blocks' barriers overlap each other's MFMA.  Same K-order as
// BK=64 (one MFMA k-chunk per iter) -> bitwise-identical accumulation.
__global__ __launch_bounds__(512, 4)
void k_gemm_v256(const u16* __restrict__ A, const u16* __restrict__ Bw,
                 const float* __restrict__ bias, float* __restrict__ Cout,
                 int gm, int N, int K, int ldc) {
  constexpr int ASTRIDE = 256 * 32;            // u16 per A buffer (16 KB)
  constexpr int BSTRIDE = 256 * 32;            // u16 per B buffer (16 KB)
  constexpr int TSTRIDE = 256 + 4;
  __shared__ __align__(16) char smem[(ASTRIDE + BSTRIDE) * 4];   // 64 KB
  u16* As = (u16*)smem;
  u16* Bs = (u16*)(smem + ASTRIDE * 4);
  float* Ts = (float*)smem;                    // epilogue alias [32][260] 33.3KB

  int lin = blockIdx.x;
  int bm = lin % gm, bn = lin / gm;            // bm fastest
  int tid = threadIdx.x, lane = tid & 63, wid = tid >> 6;  // 8 waves
  int wr = wid >> 2, wc = wid & 3;             // 2 x 4 wave grid (128x64 each)
  int fr = lane & 15, q = lane >> 4;
  f32x4 acc[8][4] = {};

  auto stage = [&](int it) {
    int buf = it & 1;
    #pragma unroll
    for (int l = 0; l < 2; l++) {              // A: 256 rows x 4 chunks / 512
      int c = tid + l * 512;
      int row = c >> 2;
      int kcg = (c & 3) ^ (row & 3);           // inverse-swizzled source chunk
      GLD(A + (size_t)(bm * 256 + row) * K + it * 32 + kcg * 8,
          (char*)(As + buf * ASTRIDE) + c * 16);
    }
    #pragma unroll
    for (int l = 0; l < 2; l++) {              // B: 256 rows x 4 chunks / 512
      int c = tid + l * 512;
      int row = c >> 2;
      int rowg = bn * 256 + row;
      if (rowg > VPAD - 1) rowg = VPAD - 1;    // clamp to zeroed pad row
      int kcg = (c & 3) ^ (row & 3);
      GLD(Bw + (size_t)rowg * K + it * 32 + kcg * 8,
          (char*)(Bs + buf * BSTRIDE) + c * 16);
    }
  };

  int nt = K >> 5;                             // 16
  stage(0);
  for (int it = 0; it < nt; ++it) {
    int cur = it & 1;
    if (it + 1 < nt) {
      stage(it + 1);                            // writes buf cur^1 (released)
      asm volatile("s_waitcnt vmcnt(4)" ::: "memory");  // stage(it) landed
    } else {
      asm volatile("s_waitcnt vmcnt(0)" ::: "memory");
    }
    __builtin_amdgcn_sched_barrier(0);
    __builtin_amdgcn_s_barrier();               // buf cur ready for all waves
    __builtin_amdgcn_sched_barrier(0);
    short8 av[8], bv[4];
    #pragma unroll
    for (int mi = 0; mi < 8; mi++) {
      int row = wr * 128 + mi * 16 + fr;
      int phys = q ^ (row & 3);
      av[mi] = *(const short8*)&As[cur * ASTRIDE + row * 32 + phys * 8];
    }
    #pragma unroll
    for (int nj = 0; nj < 4; nj++) {
      int row = wc * 64 + nj * 16 + fr;
      int phys = q ^ (row & 3);
      bv[nj] = *(const short8*)&Bs[cur * BSTRIDE + row * 32 + phys * 8];
    }
    #pragma unroll
    for (int mi = 0; mi < 8; mi++)
      #pragma unroll
      for (int nj = 0; nj < 4; nj++)
        acc[mi][nj] = __builtin_amdgcn_mfma_f32_16x16x32_bf16(
            av[mi], bv[nj], acc[mi][nj], 0, 0, 0);
    asm volatile("s_waitcnt lgkmcnt(0)" ::: "memory");  // my reads done
    __builtin_amdgcn_sched_barrier(0);
    __builtin_amdgcn_s_barrier();               // buf cur released for restage
    __builtin_amdgcn_sched_barrier(0);
  }

  // epilogue: per mi, 32 rows x 256 cols slab via LDS -> coalesced f32 stores
  float bb[4];
  #pragma unroll
  for (int nj = 0; nj < 4; nj++) {
    int cg = bn * 256 + wc * 64 + nj * 16 + fr;
    bb[nj] = (cg < N) ? bias[cg] : 0.0f;
  }
  int rl0 = (lane >> 4) * 4;
  #pragma unroll
  for (int mi = 0; mi < 8; mi++) {
    #pragma unroll
    for (int nj = 0; nj < 4; nj++) {
      int colL = wc * 64 + nj * 16 + fr;
      #pragma unroll
      for (int r = 0; r < 4; r++)
        Ts[(wr * 16 + rl0 + r) * TSTRIDE + colL] = acc[mi][nj][r] + bb[nj];
    }
    __syncthreads();
    #pragma unroll
    for (int i = 0; i < 16; i++) {             // 32*256 f32 / 512 thr
      int flat = i * 512 + tid;
      int rowf = flat >> 8, col = flat & 255;
      float v = Ts[rowf * TSTRIDE + col];
      int row_g = bm * 256 + (rowf >> 4) * 128 + mi * 16 + (rowf & 15);
      int col_g = bn * 256 + col;
      if (col_g < N)
        Cout[(size_t)row_g * ldc + col_g] = v;
    }
    if (mi < 7) __syncthreads();
  }
}

// =============================================================================
extern "C" void kernel_launch(void* const* d_in, const int* in_sizes, int n_in,
                              void* d_out, int out_size, void* d_ws, size_t ws_size,
                              hipStream_t stream) {
  const float* z        = (const float*)d_in[0];
  const int*   ids      = (const int*)d_in[1];
  const float* tok      = (const float*)d_in[2];
  const float* pos      = (const float*)d_in[3];
  const float* lp_w     = (const float*)d_in[4];
  const float* lp_b     = (const float*)d_in[5];
  const float* lp_g     = (const float*)d_in[6];
  const float* lp_be    = (const float*)d_in[7];
  const float* sa_qkv_w = (const float*)d_in[8];
  const float* sa_qkv_b = (const float*)d_in[9];
  const float* sa_out_w = (const float*)d_in[10];
  const float* sa_out_b = (const float*)d_in[11];
  const float* ca_qkv_w = (const float*)d_in[12];
  const float* ca_qkv_b = (const float*)d_in[13];
  const float* ca_out_w = (const float*)d_in[14];
  const float* ca_out_b = (const float*)d_in[15];
  const float* ln1_g    = (const float*)d_in[16];
  const float* ln1_b    = (const float*)d_in[17];
  const float* ln2_g    = (const float*)d_in[18];
  const float* ln2_b    = (const float*)d_in[19];
  const float* ln3_g    = (const float*)d_in[20];
  const float* ln3_b    = (const float*)d_in[21];
  const float* ff1_w    = (const float*)d_in[22];
  const float* ff1_b    = (const float*)d_in[23];
  const float* ff2_w    = (const float*)d_in[24];
  const float* ff2_b    = (const float*)d_in[25];
  const float* op_w     = (const float*)d_in[26];
  const float* op_b     = (const float*)d_in[27];

  char* ws = (char*)d_ws;
  u16*   Yb     = (u16*)(ws + 8388608);       // 4096x512 bf16
  u16*   QKVb   = (u16*)(ws + 16777216);      // 4096x1536 bf16
  u16*   Xb     = (u16*)(ws + 29360128);      // 4096x512 bf16 (residual stream)
  u16*   Ob     = (u16*)(ws + 33554432);      // 4096x512 bf16
  u16*   H1b    = (u16*)(ws + 37748736);      // 4096x2048 bf16
  float* ca_add = (float*)(ws + 54657024);    // 4x32x512 f32
  u16*   Wa     = (u16*)(ws + 55050240);      // weight arena bf16 (contiguous)

  u16* Wqkv = Wa;                              // 4 x 1536x512
  u16* Wout = Wa + 3145728;                    // 4 x 512x512
  u16* Wff1 = Wa + 4194304;                    // 4 x 2048x512
  u16* Wff2 = Wa + 8388608;                    // 4 x 512x2048
  u16* Wop  = Wa + 12582912;                   // 50304x512 (zero-padded tail)

  k_ca<<<4 * Bn, 256, 0, stream>>>(z, lp_w, lp_b, lp_g, lp_be,
                                   ca_qkv_w, ca_qkv_b, ca_out_w, ca_out_b, ca_add);
  k_embed<<<Bn * Ln, 128, 0, stream>>>(ids, tok, pos, Xb);
  k_cvt_all<<<2048, 256, 0, stream>>>(sa_qkv_w, sa_out_w, ff1_w, ff2_w, op_w,
                                      (us4*)Wa);

  const int M = Bn * Ln;  // 4096
  for (int i = 0; i < 4; i++) {
    k_gemm_bt<2, 128><<<32 * 12, 256, 0, stream>>>(
        Xb, Wqkv + (size_t)i * 1536 * Dn, sa_qkv_b + i * 1536, QKVb, 32, 1536, Dn, 1536);
    k_attn_m<<<Bn * Hn, 256, 0, stream>>>(QKVb, Ob);
    k_gemm_bt<2, 64><<<32 * 8, 256, 0, stream>>>(
        Ob, Wout + (size_t)i * Dn * Dn, sa_out_b + i * Dn, Yb, 32, Dn, Dn, Dn);
    k_add_ln12<<<M, 128, 0, stream>>>(Xb, Yb, ca_add + (size_t)i * Bn * Dn,
                                      ln1_g + i * Dn, ln1_b + i * Dn,
                                      ln2_g + i * Dn, ln2_b + i * Dn);
    k_gemm_bt<1, 128><<<32 * 16, 256, 0, stream>>>(
        Xb, Wff1 + (size_t)i * DFn * Dn, ff1_b + i * DFn, H1b, 32, DFn, Dn, DFn);
    k_gemm_bt<2, 64><<<32 * 8, 256, 0, stream>>>(
        H1b, Wff2 + (size_t)i * Dn * DFn, ff2_b + i * Dn, Yb, 32, Dn, DFn, Dn);
    k_add_ln<<<M, 128, 0, stream>>>(Xb, Yb, ln3_g + i * Dn, ln3_b + i * Dn);
  }

  // final vocab projection -> d_out (f32): 256x256 tiles, BK=32, 16 x 197 grid
  k_gemm_v256<<<16 * 197, 512, 0, stream>>>(
      Xb, Wop, op_b, (float*)d_out, 16, Vn, Dn, Vn);
}

// Round 15
// 813.274 us; speedup vs baseline: 2.2506x; 2.2506x over previous
//
#include <hip/hip_runtime.h>
#include <math.h>

typedef __attribute__((ext_vector_type(8))) short short8;
typedef __attribute__((ext_vector_type(4))) float f32x4;
typedef __attribute__((ext_vector_type(4))) float f4;
typedef __attribute__((ext_vector_type(4))) unsigned short us4;
typedef unsigned short u16;

#define Bn 32
#define Ln 128
#define Dn 512
#define LATn 256
#define Vn 50257
#define VPAD 50304
#define DFn 2048
#define Hn 8
#define HDn 64

#define GLD(src, dst) __builtin_amdgcn_global_load_lds( \
    (const __attribute__((address_space(1))) unsigned int*)(src), \
    (__attribute__((address_space(3))) unsigned int*)(dst), 16, 0, 0)

__device__ __forceinline__ u16 f2bf(float f) {
  union { float f; unsigned u; } v; v.f = f;
  unsigned r = 0x7FFFu + ((v.u >> 16) & 1u);
  return (u16)((v.u + r) >> 16);
}
__device__ __forceinline__ float bf2f(u16 u) {
  union { unsigned u; float f; } v; v.u = ((unsigned)u) << 16;
  return v.f;
}

// ---------------- all weights f32 -> bf16, one kernel (contiguous dst arena) -
__global__ __launch_bounds__(256)
void k_cvt_all(const float* __restrict__ s0, const float* __restrict__ s1,
               const float* __restrict__ s2, const float* __restrict__ s3,
               const float* __restrict__ s4, us4* __restrict__ dst) {
  const int C0 = 786432;    // qkv  4*1536*512/4
  const int C1 = 1048576;   // +out 4*512*512/4
  const int C2 = 2097152;   // +ff1 4*2048*512/4
  const int C3 = 3145728;   // +ff2
  const int C4 = 9584640;   // +op (VPAD*512/4)
  const int OPN4 = 6432896; // op real Vn*512/4
  int i = blockIdx.x * blockDim.x + threadIdx.x;
  int stride = gridDim.x * blockDim.x;
  for (; i < C4; i += stride) {
    const f4* src; int off; bool valid = true;
    if (i < C0)      { src = (const f4*)s0; off = i; }
    else if (i < C1) { src = (const f4*)s1; off = i - C0; }
    else if (i < C2) { src = (const f4*)s2; off = i - C1; }
    else if (i < C3) { src = (const f4*)s3; off = i - C2; }
    else             { src = (const f4*)s4; off = i - C3; valid = off < OPN4; }
    us4 o;
    if (valid) {
      f4 v = src[off];
      o[0] = f2bf(v[0]); o[1] = f2bf(v[1]); o[2] = f2bf(v[2]); o[3] = f2bf(v[3]);
    } else { o[0] = 0; o[1] = 0; o[2] = 0; o[3] = 0; }
    dst[i] = o;
  }
}

// ------------- cross-attention precompute, latent_proj fused in --------------
__global__ __launch_bounds__(256)
void k_ca(const float* __restrict__ z, const float* __restrict__ lp_w,
          const float* __restrict__ lp_b, const float* __restrict__ lp_g,
          const float* __restrict__ lp_be,
          const float* __restrict__ ca_qkv_w, const float* __restrict__ ca_qkv_b,
          const float* __restrict__ ca_out_w, const float* __restrict__ ca_out_b,
          float* __restrict__ ca_add) {
  int blk = blockIdx.x;
  int i = blk >> 5, b = blk & 31, t = threadIdx.x;
  __shared__ float zs[LATn];
  __shared__ float red[16];
  __shared__ float ms[Dn];
  __shared__ float vs[Dn];
  zs[t] = z[b * LATn + t];
  __syncthreads();
  float h[2];
  #pragma unroll
  for (int j = 0; j < 2; j++) {
    int oj = t + j * 256;
    const float* w = lp_w + (size_t)oj * LATn;
    float s0 = 0, s1 = 0, s2 = 0, s3 = 0;
    for (int k = 0; k < LATn; k += 4) {
      s0 += zs[k] * w[k]; s1 += zs[k+1] * w[k+1];
      s2 += zs[k+2] * w[k+2]; s3 += zs[k+3] * w[k+3];
    }
    float x = s0 + s1 + s2 + s3 + lp_b[oj];
    h[j] = 0.5f * x * (1.0f + erff(x * 0.70710678118654752f));
  }
  float sum = h[0] + h[1], sq = h[0]*h[0] + h[1]*h[1];
  for (int off = 32; off; off >>= 1) {
    sum += __shfl_down(sum, off, 64);
    sq  += __shfl_down(sq,  off, 64);
  }
  int lane = t & 63, wid = t >> 6;
  if (!lane) { red[wid] = sum; red[8 + wid] = sq; }
  __syncthreads();
  float ts = red[0] + red[1] + red[2] + red[3];
  float tq = red[8] + red[9] + red[10] + red[11];
  float mu = ts * (1.0f / Dn);
  float var = tq * (1.0f / Dn) - mu * mu;
  float rstd = rsqrtf(fmaxf(var, 0.0f) + 1e-5f);
  #pragma unroll
  for (int j = 0; j < 2; j++) {
    int oj = t + j * 256;
    ms[oj] = (h[j] - mu) * rstd * lp_g[oj] + lp_be[oj];
  }
  __syncthreads();
  const float* wv = ca_qkv_w + ((size_t)i * 1536 + 1024) * Dn;
  const float* bv = ca_qkv_b + i * 1536 + 1024;
  for (int j = t; j < Dn; j += 256) {
    const float* w = wv + (size_t)j * Dn;
    float s0 = 0, s1 = 0, s2 = 0, s3 = 0;
    for (int k = 0; k < Dn; k += 4) {
      s0 += ms[k]*w[k]; s1 += ms[k+1]*w[k+1]; s2 += ms[k+2]*w[k+2]; s3 += ms[k+3]*w[k+3];
    }
    vs[j] = s0 + s1 + s2 + s3 + bv[j];
  }
  __syncthreads();
  const float* wo = ca_out_w + (size_t)i * Dn * Dn;
  const float* bo = ca_out_b + i * Dn;
  for (int j = t; j < Dn; j += 256) {
    const float* w = wo + (size_t)j * Dn;
    float s0 = 0, s1 = 0, s2 = 0, s3 = 0;
    for (int k = 0; k < Dn; k += 4) {
      s0 += vs[k]*w[k]; s1 += vs[k+1]*w[k+1]; s2 += vs[k+2]*w[k+2]; s3 += vs[k+3]*w[k+3];
    }
    ca_add[((size_t)i * Bn + b) * Dn + j] = s0 + s1 + s2 + s3 + bo[j];
  }
}

// ---------------- embedding: Xb = bf16(tok_emb[ids] + pos_emb) ---------------
__global__ __launch_bounds__(128)
void k_embed(const int* __restrict__ ids, const float* __restrict__ tok,
             const float* __restrict__ pos, u16* __restrict__ Xb) {
  int r = blockIdx.x;
  int l = r & (Ln - 1);
  int id = ids[r];
  int c = threadIdx.x * 4;
  f4 te = *(const f4*)&tok[(size_t)id * Dn + c];
  f4 pe = *(const f4*)&pos[(size_t)l * Dn + c];
  f4 v = te + pe;
  us4 o = { f2bf(v[0]), f2bf(v[1]), f2bf(v[2]), f2bf(v[3]) };
  *(us4*)&Xb[(size_t)r * Dn + c] = o;
}

// ------- fused residual add + LayerNorm, single-wave (no LDS, no barriers) ---
__global__ __launch_bounds__(64)
void k_add_ln(u16* __restrict__ Xb, const u16* __restrict__ Y,
              const float* __restrict__ g, const float* __restrict__ be) {
  int r = blockIdx.x, t = threadIdx.x;
  int c = t * 8;
  short8 xb = *(const short8*)&Xb[(size_t)r * Dn + c];
  short8 yb = *(const short8*)&Y[(size_t)r * Dn + c];
  float v[8];
  float sum = 0, sq = 0;
  #pragma unroll
  for (int j = 0; j < 8; j++) {
    v[j] = bf2f((u16)xb[j]) + bf2f((u16)yb[j]);
    sum += v[j]; sq += v[j] * v[j];
  }
  #pragma unroll
  for (int off = 32; off; off >>= 1) {
    sum += __shfl_xor(sum, off, 64);
    sq  += __shfl_xor(sq,  off, 64);
  }
  float mu = sum * (1.0f / Dn);
  float var = sq * (1.0f / Dn) - mu * mu;
  float rstd = rsqrtf(fmaxf(var, 0.0f) + 1e-5f);
  f4 g0 = *(const f4*)&g[c], g1 = *(const f4*)&g[c + 4];
  f4 b0 = *(const f4*)&be[c], b1 = *(const f4*)&be[c + 4];
  short8 ob;
  #pragma unroll
  for (int j = 0; j < 4; j++) {
    ob[j]     = (short)f2bf((v[j]     - mu) * rstd * g0[j] + b0[j]);
    ob[j + 4] = (short)f2bf((v[j + 4] - mu) * rstd * g1[j] + b1[j]);
  }
  *(short8*)&Xb[(size_t)r * Dn + c] = ob;
}

// ------- fused LN1(X+Y) then LN2(. + CA), single-wave ------------------------
__global__ __launch_bounds__(64)
void k_add_ln12(u16* __restrict__ Xb, const u16* __restrict__ Y,
                const float* __restrict__ CA,
                const float* __restrict__ g1, const float* __restrict__ b1,
                const float* __restrict__ g2, const float* __restrict__ b2) {
  int r = blockIdx.x, t = threadIdx.x;
  int c = t * 8;
  short8 xb = *(const short8*)&Xb[(size_t)r * Dn + c];
  short8 yb = *(const short8*)&Y[(size_t)r * Dn + c];
  float v[8];
  float sum = 0, sq = 0;
  #pragma unroll
  for (int j = 0; j < 8; j++) {
    v[j] = bf2f((u16)xb[j]) + bf2f((u16)yb[j]);
    sum += v[j]; sq += v[j] * v[j];
  }
  #pragma unroll
  for (int off = 32; off; off >>= 1) {
    sum += __shfl_xor(sum, off, 64);
    sq  += __shfl_xor(sq,  off, 64);
  }
  float mu = sum * (1.0f / Dn);
  float var = sq * (1.0f / Dn) - mu * mu;
  float rstd = rsqrtf(fmaxf(var, 0.0f) + 1e-5f);
  const float* car = CA + (size_t)(r >> 7) * Dn + c;
  f4 ca0 = *(const f4*)&car[0], ca1 = *(const f4*)&car[4];
  f4 g1a = *(const f4*)&g1[c], g1b = *(const f4*)&g1[c + 4];
  f4 b1a = *(const f4*)&b1[c], b1b = *(const f4*)&b1[c + 4];
  float v2[8];
  float sum2 = 0, sq2 = 0;
  #pragma unroll
  for (int j = 0; j < 4; j++) {
    v2[j]     = (v[j]     - mu) * rstd * g1a[j] + b1a[j] + ca0[j];
    v2[j + 4] = (v[j + 4] - mu) * rstd * g1b[j] + b1b[j] + ca1[j];
  }
  #pragma unroll
  for (int j = 0; j < 8; j++) { sum2 += v2[j]; sq2 += v2[j] * v2[j]; }
  #pragma unroll
  for (int off = 32; off; off >>= 1) {
    sum2 += __shfl_xor(sum2, off, 64);
    sq2  += __shfl_xor(sq2,  off, 64);
  }
  float mu2 = sum2 * (1.0f / Dn);
  float var2 = sq2 * (1.0f / Dn) - mu2 * mu2;
  float rstd2 = rsqrtf(fmaxf(var2, 0.0f) + 1e-5f);
  f4 g2a = *(const f4*)&g2[c], g2b = *(const f4*)&g2[c + 4];
  f4 b2a = *(const f4*)&b2[c], b2b = *(const f4*)&b2[c + 4];
  short8 ob;
  #pragma unroll
  for (int j = 0; j < 4; j++) {
    ob[j]     = (short)f2bf((v2[j]     - mu2) * rstd2 * g2a[j] + b2a[j]);
    ob[j + 4] = (short)f2bf((v2[j + 4] - mu2) * rstd2 * g2b[j] + b2b[j]);
  }
  *(short8*)&Xb[(size_t)r * Dn + c] = ob;
}

// ---------------- MFMA causal attention (R9-R13 passing kernel, unchanged) ---
__global__ __launch_bounds__(256, 1)
void k_attn_m(const u16* __restrict__ QKV, u16* __restrict__ Ob) {
  constexpr int QS = 0;
  constexpr int KS = 9216;
  constexpr int SFB = 36864;
  constexpr int VTB = 36864 + 66048;
  constexpr int MXB = VTB + 17408;
  constexpr int LXB = MXB + 1024;
  __shared__ __align__(16) char smem[LXB + 1024];
  u16* U = (u16*)smem;
  float* Sf = (float*)(smem + SFB);
  u16* Vt = (u16*)(smem + VTB);
  float* Mx = (float*)(smem + MXB);
  float* Lx = (float*)(smem + LXB);

  int bh = blockIdx.x, b = bh >> 3, h = bh & 7;
  int tid = threadIdx.x, lane = tid & 63, wid = tid >> 6;
  int r = tid & 127, half = tid >> 7;

  {
    const u16* qk = QKV + (size_t)(b * 128 + r) * 1536 + (half ? 512 : 0) + h * 64;
    u16* dst = U + (half ? KS : QS) + r * 72;
    #pragma unroll
    for (int i = 0; i < 64; i += 8)
      *(short8*)(dst + i) = *(const short8*)(qk + i);
    const u16* vsrc = QKV + (size_t)(b * 128 + r) * 1536 + 1024 + h * 64 + half * 32;
    #pragma unroll
    for (int i = 0; i < 32; i += 8) {
      short8 v = *(const short8*)(vsrc + i);
      #pragma unroll
      for (int j = 0; j < 8; j++)
        Vt[(half * 32 + i + j) * 136 + r] = (u16)v[j];
    }
  }
  __syncthreads();

  int qb = wid * 32;
  int fr = lane & 15, qk8 = (lane >> 4) * 8, qrl = (lane >> 4) * 4;
  f32x4 sacc[2][8] = {};
  #pragma unroll
  for (int s = 0; s < 2; s++) {
    short8 av[2], bv[8];
    #pragma unroll
    for (int mi = 0; mi < 2; mi++)
      av[mi] = *(const short8*)(U + QS + (qb + mi * 16 + fr) * 72 + s * 32 + qk8);
    #pragma unroll
    for (int nj = 0; nj < 8; nj++)
      bv[nj] = *(const short8*)(U + KS + (nj * 16 + fr) * 72 + s * 32 + qk8);
    #pragma unroll
    for (int mi = 0; mi < 2; mi++)
      #pragma unroll
      for (int nj = 0; nj < 8; nj++)
        sacc[mi][nj] = __builtin_amdgcn_mfma_f32_16x16x32_bf16(
            av[mi], bv[nj], sacc[mi][nj], 0, 0, 0);
  }
  #pragma unroll
  for (int mi = 0; mi < 2; mi++)
    #pragma unroll
    for (int nj = 0; nj < 8; nj++)
      #pragma unroll
      for (int g = 0; g < 4; g++) {
        int q = qb + mi * 16 + qrl + g;
        int k = nj * 16 + fr;
        Sf[q * 129 + k] = (k <= q) ? sacc[mi][nj][g] * 0.125f : -1e30f;
      }
  __syncthreads();

  int kr = half * 64;
  float m = -1e30f;
  for (int k = 0; k < 64; k++) m = fmaxf(m, Sf[r * 129 + kr + k]);
  Mx[half * 128 + r] = m;
  __syncthreads();
  float mm = fmaxf(Mx[r], Mx[128 + r]);
  float l = 0.0f;
  for (int k = 0; k < 64; k++) {
    float p = __expf(Sf[r * 129 + kr + k] - mm);
    Sf[r * 129 + kr + k] = p;
    l += p;
  }
  Lx[half * 128 + r] = l;
  __syncthreads();
  float linv = 1.0f / (Lx[r] + Lx[128 + r]);
  #pragma unroll
  for (int kc = 0; kc < 8; kc++) {
    short8 pv;
    #pragma unroll
    for (int j = 0; j < 8; j++)
      pv[j] = (short)f2bf(Sf[r * 129 + kr + kc * 8 + j] * linv);
    *(short8*)(U + r * 136 + kr + kc * 8) = pv;
  }
  __syncthreads();

  f32x4 oacc[2][4] = {};
  #pragma unroll
  for (int ks = 0; ks < 4; ks++) {
    short8 av[2], bv[4];
    #pragma unroll
    for (int mi = 0; mi < 2; mi++)
      av[mi] = *(const short8*)(U + (qb + mi * 16 + fr) * 136 + ks * 32 + qk8);
    #pragma unroll
    for (int nj = 0; nj < 4; nj++)
      bv[nj] = *(const short8*)(Vt + (nj * 16 + fr) * 136 + ks * 32 + qk8);
    #pragma unroll
    for (int mi = 0; mi < 2; mi++)
      #pragma unroll
      for (int nj = 0; nj < 4; nj++)
        oacc[mi][nj] = __builtin_amdgcn_mfma_f32_16x16x32_bf16(
            av[mi], bv[nj], oacc[mi][nj], 0, 0, 0);
  }
  #pragma unroll
  for (int mi = 0; mi < 2; mi++)
    #pragma unroll
    for (int nj = 0; nj < 4; nj++)
      #pragma unroll
      for (int g = 0; g < 4; g++) {
        int q = qb + mi * 16 + qrl + g;
        int d = nj * 16 + fr;
        Ob[(size_t)(b * 128 + q) * 512 + h * 64 + d] = f2bf(oacc[mi][nj][g]);
      }
}

// ---------------- layer GEMM (R8-R13 passing kernel, unchanged) --------------
template <int EPI, int BNT>
__global__ __launch_bounds__(256, (BNT == 128 ? 2 : 3))
void k_gemm_bt(const u16* __restrict__ A, const u16* __restrict__ Bw,
               const float* __restrict__ bias, void* __restrict__ Cout,
               int gm, int N, int K, int ldc) {
  constexpr int NREP = BNT / 32;
  constexpr int ASTRIDE = 128 * 64;
  constexpr int BSTRIDE = BNT * 64;
  constexpr int TSTRIDE = BNT + 4;
  constexpr int NLA = 4;
  constexpr int NLB = BNT / 32;
  __shared__ __align__(16) char smem[(ASTRIDE + BSTRIDE) * 4];
  u16* As = (u16*)smem;
  u16* Bs = (u16*)(smem + ASTRIDE * 4);
  float* Ts = (float*)smem;

  int lin = blockIdx.x;
  int bm = lin % gm, bn = lin / gm;
  int tid = threadIdx.x, lane = tid & 63, wid = tid >> 6;
  int wr = wid >> 1, wc = wid & 1;
  int fr = lane & 15, q = lane >> 4;
  f32x4 acc[4][NREP] = {};

  auto stage = [&](int it) {
    int buf = it & 1;
    #pragma unroll
    for (int l = 0; l < NLA; l++) {
      int c = tid + l * 256;
      int row = c >> 3;
      int kcg = (c & 7) ^ (row & 7);
      GLD(A + (size_t)(bm * 128 + row) * K + it * 64 + kcg * 8,
          (char*)(As + buf * ASTRIDE) + c * 16);
    }
    #pragma unroll
    for (int l = 0; l < NLB; l++) {
      int c = tid + l * 256;
      int row = c >> 3;
      int kcg = (c & 7) ^ (row & 7);
      GLD(Bw + (size_t)(bn * BNT + row) * K + it * 64 + kcg * 8,
          (char*)(Bs + buf * BSTRIDE) + c * 16);
    }
  };

  int nt = K >> 6;
  stage(0);
  for (int it = 0; it < nt; ++it) {
    int cur = it & 1;
    if (it + 1 < nt) {
      stage(it + 1);
      if constexpr (BNT == 128) asm volatile("s_waitcnt vmcnt(8)" ::: "memory");
      else                      asm volatile("s_waitcnt vmcnt(6)" ::: "memory");
    } else {
      asm volatile("s_waitcnt vmcnt(0)" ::: "memory");
    }
    __builtin_amdgcn_sched_barrier(0);
    __builtin_amdgcn_s_barrier();
    __builtin_amdgcn_sched_barrier(0);
    short8 av[2][4], bv[2][NREP];
    #pragma unroll
    for (int s = 0; s < 2; s++) {
      #pragma unroll
      for (int mi = 0; mi < 4; mi++) {
        int row = wr * 64 + mi * 16 + fr;
        int phys = (s * 4 + q) ^ (row & 7);
        av[s][mi] = *(const short8*)&As[cur * ASTRIDE + row * 64 + phys * 8];
      }
      #pragma unroll
      for (int nj = 0; nj < NREP; nj++) {
        int row = wc * (BNT / 2) + nj * 16 + fr;
        int phys = (s * 4 + q) ^ (row & 7);
        bv[s][nj] = *(const short8*)&Bs[cur * BSTRIDE + row * 64 + phys * 8];
      }
    }
    #pragma unroll
    for (int s = 0; s < 2; s++)
      #pragma unroll
      for (int mi = 0; mi < 4; mi++)
        #pragma unroll
        for (int nj = 0; nj < NREP; nj++)
          acc[mi][nj] = __builtin_amdgcn_mfma_f32_16x16x32_bf16(
              av[s][mi], bv[s][nj], acc[mi][nj], 0, 0, 0);
    asm volatile("s_waitcnt lgkmcnt(0)" ::: "memory");
    __builtin_amdgcn_sched_barrier(0);
    __builtin_amdgcn_s_barrier();
    __builtin_amdgcn_sched_barrier(0);
  }

  float bb[NREP];
  #pragma unroll
  for (int nj = 0; nj < NREP; nj++) {
    int cg = bn * BNT + wc * (BNT / 2) + nj * 16 + fr;
    bb[nj] = (cg < N) ? bias[cg] : 0.0f;
  }
  int rl0 = (lane >> 4) * 4;
  #pragma unroll
  for (int mi = 0; mi < 4; mi++) {
    #pragma unroll
    for (int nj = 0; nj < NREP; nj++) {
      int colL = wc * (BNT / 2) + nj * 16 + fr;
      #pragma unroll
      for (int r = 0; r < 4; r++)
        Ts[(wr * 16 + rl0 + r) * TSTRIDE + colL] = acc[mi][nj][r] + bb[nj];
    }
    __syncthreads();
    constexpr int ITERS = (32 * BNT) / 256;
    #pragma unroll
    for (int i = 0; i < ITERS; i++) {
      int flat = i * 256 + tid;
      int rowf = flat / BNT, col = flat % BNT;
      float v = Ts[rowf * TSTRIDE + col];
      int row_g = bm * 128 + (rowf >> 4) * 64 + mi * 16 + (rowf & 15);
      int col_g = bn * BNT + col;
      size_t off = (size_t)row_g * ldc + col_g;
      if (EPI == 0) {
        if (col_g < N) ((float*)Cout)[off] = v;
      } else if (EPI == 1) {
        ((u16*)Cout)[off] = f2bf(fmaxf(v, 0.0f));
      } else {
        ((u16*)Cout)[off] = f2bf(v);
      }
    }
    if (mi < 3) __syncthreads();
  }
}

// ---------------- vocab GEMM: 256x256 tile, BK=64, 8 waves (R13-exact) -------
__global__ __launch_bounds__(512, 2)
void k_gemm_v256(const u16* __restrict__ A, const u16* __restrict__ Bw,
                 const float* __restrict__ bias, float* __restrict__ Cout,
                 int gm, int N, int K, int ldc) {
  constexpr int ASTRIDE = 256 * 64;            // u16 per A buffer (32 KB)
  constexpr int BSTRIDE = 256 * 64;            // u16 per B buffer (32 KB)
  constexpr int TSTRIDE = 256 + 4;
  __shared__ __align__(16) char smem[(ASTRIDE + BSTRIDE) * 4];   // 128 KB
  u16* As = (u16*)smem;
  u16* Bs = (u16*)(smem + ASTRIDE * 4);
  float* Ts = (float*)smem;                    // epilogue alias [32][260]

  int lin = blockIdx.x;
  int bm = lin % gm, bn = lin / gm;            // bm fastest
  int tid = threadIdx.x, lane = tid & 63, wid = tid >> 6;  // 8 waves
  int wr = wid >> 2, wc = wid & 3;             // 2 x 4 wave grid (128x64 each)
  int fr = lane & 15, q = lane >> 4;
  f32x4 acc[8][4] = {};

  auto stage = [&](int it) {
    int buf = it & 1;
    #pragma unroll
    for (int l = 0; l < 4; l++) {              // A: 256 rows x 8 chunks / 512
      int c = tid + l * 512;
      int row = c >> 3;
      int kcg = (c & 7) ^ (row & 7);
      GLD(A + (size_t)(bm * 256 + row) * K + it * 64 + kcg * 8,
          (char*)(As + buf * ASTRIDE) + c * 16);
    }
    #pragma unroll
    for (int l = 0; l < 4; l++) {              // B: 256 rows x 8 chunks / 512
      int c = tid + l * 512;
      int row = c >> 3;
      int rowg = bn * 256 + row;
      if (rowg > VPAD - 1) rowg = VPAD - 1;    // clamp to zeroed pad row
      int kcg = (c & 7) ^ (row & 7);
      GLD(Bw + (size_t)rowg * K + it * 64 + kcg * 8,
          (char*)(Bs + buf * BSTRIDE) + c * 16);
    }
  };

  int nt = K >> 6;
  stage(0);
  for (int it = 0; it < nt; ++it) {
    int cur = it & 1;
    if (it + 1 < nt) {
      stage(it + 1);                            // writes buf cur^1 (released)
      asm volatile("s_waitcnt vmcnt(8)" ::: "memory");  // stage(it) landed
    } else {
      asm volatile("s_waitcnt vmcnt(0)" ::: "memory");
    }
    __builtin_amdgcn_sched_barrier(0);
    __builtin_amdgcn_s_barrier();               // buf cur ready for all waves
    __builtin_amdgcn_sched_barrier(0);
    #pragma unroll
    for (int s = 0; s < 2; s++) {
      short8 av[8], bv[4];
      #pragma unroll
      for (int mi = 0; mi < 8; mi++) {
        int row = wr * 128 + mi * 16 + fr;
        int phys = (s * 4 + q) ^ (row & 7);
        av[mi] = *(const short8*)&As[cur * ASTRIDE + row * 64 + phys * 8];
      }
      #pragma unroll
      for (int nj = 0; nj < 4; nj++) {
        int row = wc * 64 + nj * 16 + fr;
        int phys = (s * 4 + q) ^ (row & 7);
        bv[nj] = *(const short8*)&Bs[cur * BSTRIDE + row * 64 + phys * 8];
      }
      #pragma unroll
      for (int mi = 0; mi < 8; mi++)
        #pragma unroll
        for (int nj = 0; nj < 4; nj++)
          acc[mi][nj] = __builtin_amdgcn_mfma_f32_16x16x32_bf16(
              av[mi], bv[nj], acc[mi][nj], 0, 0, 0);
    }
    asm volatile("s_waitcnt lgkmcnt(0)" ::: "memory");  // my reads done
    __builtin_amdgcn_sched_barrier(0);
    __builtin_amdgcn_s_barrier();               // buf cur released for restage
    __builtin_amdgcn_sched_barrier(0);
  }

  // epilogue: per mi, 32 rows x 256 cols slab via LDS -> coalesced f32 stores
  float bb[4];
  #pragma unroll
  for (int nj = 0; nj < 4; nj++) {
    int cg = bn * 256 + wc * 64 + nj * 16 + fr;
    bb[nj] = (cg < N) ? bias[cg] : 0.0f;
  }
  int rl0 = (lane >> 4) * 4;
  #pragma unroll
  for (int mi = 0; mi < 8; mi++) {
    #pragma unroll
    for (int nj = 0; nj < 4; nj++) {
      int colL = wc * 64 + nj * 16 + fr;
      #pragma unroll
      for (int r = 0; r < 4; r++)
        Ts[(wr * 16 + rl0 + r) * TSTRIDE + colL] = acc[mi][nj][r] + bb[nj];
    }
    __syncthreads();
    #pragma unroll
    for (int i = 0; i < 16; i++) {             // 32*256 f32 / 512 thr
      int flat = i * 512 + tid;
      int rowf = flat >> 8, col = flat & 255;
      float v = Ts[rowf * TSTRIDE + col];
      int row_g = bm * 256 + (rowf >> 4) * 128 + mi * 16 + (rowf & 15);
      int col_g = bn * 256 + col;
      if (col_g < N)
        Cout[(size_t)row_g * ldc + col_g] = v;
    }
    if (mi < 7) __syncthreads();
  }
}

// =============================================================================
extern "C" void kernel_launch(void* const* d_in, const int* in_sizes, int n_in,
                              void* d_out, int out_size, void* d_ws, size_t ws_size,
                              hipStream_t stream) {
  const float* z        = (const float*)d_in[0];
  const int*   ids      = (const int*)d_in[1];
  const float* tok      = (const float*)d_in[2];
  const float* pos      = (const float*)d_in[3];
  const float* lp_w     = (const float*)d_in[4];
  const float* lp_b     = (const float*)d_in[5];
  const float* lp_g     = (const float*)d_in[6];
  const float* lp_be    = (const float*)d_in[7];
  const float* sa_qkv_w = (const float*)d_in[8];
  const float* sa_qkv_b = (const float*)d_in[9];
  const float* sa_out_w = (const float*)d_in[10];
  const float* sa_out_b = (const float*)d_in[11];
  const float* ca_qkv_w = (const float*)d_in[12];
  const float* ca_qkv_b = (const float*)d_in[13];
  const float* ca_out_w = (const float*)d_in[14];
  const float* ca_out_b = (const float*)d_in[15];
  const float* ln1_g    = (const float*)d_in[16];
  const float* ln1_b    = (const float*)d_in[17];
  const float* ln2_g    = (const float*)d_in[18];
  const float* ln2_b    = (const float*)d_in[19];
  const float* ln3_g    = (const float*)d_in[20];
  const float* ln3_b    = (const float*)d_in[21];
  const float* ff1_w    = (const float*)d_in[22];
  const float* ff1_b    = (const float*)d_in[23];
  const float* ff2_w    = (const float*)d_in[24];
  const float* ff2_b    = (const float*)d_in[25];
  const float* op_w     = (const float*)d_in[26];
  const float* op_b     = (const float*)d_in[27];

  char* ws = (char*)d_ws;
  u16*   Yb     = (u16*)(ws + 8388608);       // 4096x512 bf16
  u16*   QKVb   = (u16*)(ws + 16777216);      // 4096x1536 bf16
  u16*   Xb     = (u16*)(ws + 29360128);      // 4096x512 bf16 (residual stream)
  u16*   Ob     = (u16*)(ws + 33554432);      // 4096x512 bf16
  u16*   H1b    = (u16*)(ws + 37748736);      // 4096x2048 bf16
  float* ca_add = (float*)(ws + 54657024);    // 4x32x512 f32
  u16*   Wa     = (u16*)(ws + 55050240);      // weight arena bf16 (contiguous)

  u16* Wqkv = Wa;                              // 4 x 1536x512
  u16* Wout = Wa + 3145728;                    // 4 x 512x512
  u16* Wff1 = Wa + 4194304;                    // 4 x 2048x512
  u16* Wff2 = Wa + 8388608;                    // 4 x 512x2048
  u16* Wop  = Wa + 12582912;                   // 50304x512 (zero-padded tail)

  k_ca<<<4 * Bn, 256, 0, stream>>>(z, lp_w, lp_b, lp_g, lp_be,
                                   ca_qkv_w, ca_qkv_b, ca_out_w, ca_out_b, ca_add);
  k_embed<<<Bn * Ln, 128, 0, stream>>>(ids, tok, pos, Xb);
  k_cvt_all<<<2048, 256, 0, stream>>>(sa_qkv_w, sa_out_w, ff1_w, ff2_w, op_w,
                                      (us4*)Wa);

  const int M = Bn * Ln;  // 4096
  for (int i = 0; i < 4; i++) {
    k_gemm_bt<2, 128><<<32 * 12, 256, 0, stream>>>(
        Xb, Wqkv + (size_t)i * 1536 * Dn, sa_qkv_b + i * 1536, QKVb, 32, 1536, Dn, 1536);
    k_attn_m<<<Bn * Hn, 256, 0, stream>>>(QKVb, Ob);
    k_gemm_bt<2, 64><<<32 * 8, 256, 0, stream>>>(
        Ob, Wout + (size_t)i * Dn * Dn, sa_out_b + i * Dn, Yb, 32, Dn, Dn, Dn);
    k_add_ln12<<<M, 64, 0, stream>>>(Xb, Yb, ca_add + (size_t)i * Bn * Dn,
                                     ln1_g + i * Dn, ln1_b + i * Dn,
                                     ln2_g + i * Dn, ln2_b + i * Dn);
    k_gemm_bt<1, 128><<<32 * 16, 256, 0, stream>>>(
        Xb, Wff1 + (size_t)i * DFn * Dn, ff1_b + i * DFn, H1b, 32, DFn, Dn, DFn);
    k_gemm_bt<2, 64><<<32 * 8, 256, 0, stream>>>(
        H1b, Wff2 + (size_t)i * Dn * DFn, ff2_b + i * Dn, Yb, 32, Dn, DFn, Dn);
    k_add_ln<<<M, 64, 0, stream>>>(Xb, Yb, ln3_g + i * Dn, ln3_b + i * Dn);
  }

  // final vocab projection -> d_out (f32): 256x256 tiles, BK=64, 16 x 197 grid
  k_gemm_v256<<<16 * 197, 512, 0, stream>>>(
      Xb, Wop, op_b, (float*)d_out, 16, Vn, Dn, Vn);
}

// Round 16
// 802.111 us; speedup vs baseline: 2.2819x; 1.0139x over previous
//
#include <hip/hip_runtime.h>
#include <math.h>

typedef __attribute__((ext_vector_type(8))) short short8;
typedef __attribute__((ext_vector_type(4))) float f32x4;
typedef __attribute__((ext_vector_type(4))) float f4;
typedef __attribute__((ext_vector_type(4))) unsigned short us4;
typedef unsigned short u16;

#define Bn 32
#define Ln 128
#define Dn 512
#define LATn 256
#define Vn 50257
#define VPAD 50304
#define DFn 2048
#define Hn 8
#define HDn 64

#define GLD(src, dst) __builtin_amdgcn_global_load_lds( \
    (const __attribute__((address_space(1))) unsigned int*)(src), \
    (__attribute__((address_space(3))) unsigned int*)(dst), 16, 0, 0)

__device__ __forceinline__ u16 f2bf(float f) {
  union { float f; unsigned u; } v; v.f = f;
  unsigned r = 0x7FFFu + ((v.u >> 16) & 1u);
  return (u16)((v.u + r) >> 16);
}
__device__ __forceinline__ float bf2f(u16 u) {
  union { unsigned u; float f; } v; v.u = ((unsigned)u) << 16;
  return v.f;
}

// ---------------- all weights f32 -> bf16, one kernel (contiguous dst arena) -
__global__ __launch_bounds__(256)
void k_cvt_all(const float* __restrict__ s0, const float* __restrict__ s1,
               const float* __restrict__ s2, const float* __restrict__ s3,
               const float* __restrict__ s4, us4* __restrict__ dst) {
  const int C0 = 786432;
  const int C1 = 1048576;
  const int C2 = 2097152;
  const int C3 = 3145728;
  const int C4 = 9584640;
  const int OPN4 = 6432896;
  int i = blockIdx.x * blockDim.x + threadIdx.x;
  int stride = gridDim.x * blockDim.x;
  for (; i < C4; i += stride) {
    const f4* src; int off; bool valid = true;
    if (i < C0)      { src = (const f4*)s0; off = i; }
    else if (i < C1) { src = (const f4*)s1; off = i - C0; }
    else if (i < C2) { src = (const f4*)s2; off = i - C1; }
    else if (i < C3) { src = (const f4*)s3; off = i - C2; }
    else             { src = (const f4*)s4; off = i - C3; valid = off < OPN4; }
    us4 o;
    if (valid) {
      f4 v = src[off];
      o[0] = f2bf(v[0]); o[1] = f2bf(v[1]); o[2] = f2bf(v[2]); o[3] = f2bf(v[3]);
    } else { o[0] = 0; o[1] = 0; o[2] = 0; o[3] = 0; }
    dst[i] = o;
  }
}

// ------------- cross-attention precompute, latent_proj fused in --------------
__global__ __launch_bounds__(256)
void k_ca(const float* __restrict__ z, const float* __restrict__ lp_w,
          const float* __restrict__ lp_b, const float* __restrict__ lp_g,
          const float* __restrict__ lp_be,
          const float* __restrict__ ca_qkv_w, const float* __restrict__ ca_qkv_b,
          const float* __restrict__ ca_out_w, const float* __restrict__ ca_out_b,
          float* __restrict__ ca_add) {
  int blk = blockIdx.x;
  int i = blk >> 5, b = blk & 31, t = threadIdx.x;
  __shared__ float zs[LATn];
  __shared__ float red[16];
  __shared__ float ms[Dn];
  __shared__ float vs[Dn];
  zs[t] = z[b * LATn + t];
  __syncthreads();
  float h[2];
  #pragma unroll
  for (int j = 0; j < 2; j++) {
    int oj = t + j * 256;
    const float* w = lp_w + (size_t)oj * LATn;
    float s0 = 0, s1 = 0, s2 = 0, s3 = 0;
    for (int k = 0; k < LATn; k += 4) {
      s0 += zs[k] * w[k]; s1 += zs[k+1] * w[k+1];
      s2 += zs[k+2] * w[k+2]; s3 += zs[k+3] * w[k+3];
    }
    float x = s0 + s1 + s2 + s3 + lp_b[oj];
    h[j] = 0.5f * x * (1.0f + erff(x * 0.70710678118654752f));
  }
  float sum = h[0] + h[1], sq = h[0]*h[0] + h[1]*h[1];
  for (int off = 32; off; off >>= 1) {
    sum += __shfl_down(sum, off, 64);
    sq  += __shfl_down(sq,  off, 64);
  }
  int lane = t & 63, wid = t >> 6;
  if (!lane) { red[wid] = sum; red[8 + wid] = sq; }
  __syncthreads();
  float ts = red[0] + red[1] + red[2] + red[3];
  float tq = red[8] + red[9] + red[10] + red[11];
  float mu = ts * (1.0f / Dn);
  float var = tq * (1.0f / Dn) - mu * mu;
  float rstd = rsqrtf(fmaxf(var, 0.0f) + 1e-5f);
  #pragma unroll
  for (int j = 0; j < 2; j++) {
    int oj = t + j * 256;
    ms[oj] = (h[j] - mu) * rstd * lp_g[oj] + lp_be[oj];
  }
  __syncthreads();
  const float* wv = ca_qkv_w + ((size_t)i * 1536 + 1024) * Dn;
  const float* bv = ca_qkv_b + i * 1536 + 1024;
  for (int j = t; j < Dn; j += 256) {
    const float* w = wv + (size_t)j * Dn;
    float s0 = 0, s1 = 0, s2 = 0, s3 = 0;
    for (int k = 0; k < Dn; k += 4) {
      s0 += ms[k]*w[k]; s1 += ms[k+1]*w[k+1]; s2 += ms[k+2]*w[k+2]; s3 += ms[k+3]*w[k+3];
    }
    vs[j] = s0 + s1 + s2 + s3 + bv[j];
  }
  __syncthreads();
  const float* wo = ca_out_w + (size_t)i * Dn * Dn;
  const float* bo = ca_out_b + i * Dn;
  for (int j = t; j < Dn; j += 256) {
    const float* w = wo + (size_t)j * Dn;
    float s0 = 0, s1 = 0, s2 = 0, s3 = 0;
    for (int k = 0; k < Dn; k += 4) {
      s0 += vs[k]*w[k]; s1 += vs[k+1]*w[k+1]; s2 += vs[k+2]*w[k+2]; s3 += vs[k+3]*w[k+3];
    }
    ca_add[((size_t)i * Bn + b) * Dn + j] = s0 + s1 + s2 + s3 + bo[j];
  }
}

// ---------------- embedding: Xb = bf16(tok_emb[ids] + pos_emb) ---------------
__global__ __launch_bounds__(128)
void k_embed(const int* __restrict__ ids, const float* __restrict__ tok,
             const float* __restrict__ pos, u16* __restrict__ Xb) {
  int r = blockIdx.x;
  int l = r & (Ln - 1);
  int id = ids[r];
  int c = threadIdx.x * 4;
  f4 te = *(const f4*)&tok[(size_t)id * Dn + c];
  f4 pe = *(const f4*)&pos[(size_t)l * Dn + c];
  f4 v = te + pe;
  us4 o = { f2bf(v[0]), f2bf(v[1]), f2bf(v[2]), f2bf(v[3]) };
  *(us4*)&Xb[(size_t)r * Dn + c] = o;
}

// ---------------- fused residual add + LayerNorm (R13 proven, 128 thr) -------
__global__ __launch_bounds__(128)
void k_add_ln(u16* __restrict__ Xb, const u16* __restrict__ Y,
              const float* __restrict__ g, const float* __restrict__ be) {
  int r = blockIdx.x, t = threadIdx.x;
  int c = t * 4;
  us4 xb = *(const us4*)&Xb[(size_t)r * Dn + c];
  us4 yb = *(const us4*)&Y[(size_t)r * Dn + c];
  f4 v;
  v[0] = bf2f(xb[0]) + bf2f(yb[0]); v[1] = bf2f(xb[1]) + bf2f(yb[1]);
  v[2] = bf2f(xb[2]) + bf2f(yb[2]); v[3] = bf2f(xb[3]) + bf2f(yb[3]);
  float sum = v[0] + v[1] + v[2] + v[3];
  float sq = v[0]*v[0] + v[1]*v[1] + v[2]*v[2] + v[3]*v[3];
  for (int off = 32; off; off >>= 1) {
    sum += __shfl_down(sum, off, 64);
    sq  += __shfl_down(sq,  off, 64);
  }
  __shared__ float red[4];
  int lane = t & 63, w = t >> 6;
  if (!lane) { red[w] = sum; red[2 + w] = sq; }
  __syncthreads();
  sum = red[0] + red[1]; sq = red[2] + red[3];
  float mu = sum * (1.0f / Dn);
  float var = sq * (1.0f / Dn) - mu * mu;
  float rstd = rsqrtf(fmaxf(var, 0.0f) + 1e-5f);
  f4 gg = *(const f4*)&g[c];
  f4 bb = *(const f4*)&be[c];
  f4 o = (v - mu) * rstd * gg + bb;
  us4 ob = { f2bf(o[0]), f2bf(o[1]), f2bf(o[2]), f2bf(o[3]) };
  *(us4*)&Xb[(size_t)r * Dn + c] = ob;
}

// ---------------- fused LN1(X+Y) then LN2(. + CA) (R13 proven) ---------------
__global__ __launch_bounds__(128)
void k_add_ln12(u16* __restrict__ Xb, const u16* __restrict__ Y,
                const float* __restrict__ CA,
                const float* __restrict__ g1, const float* __restrict__ b1,
                const float* __restrict__ g2, const float* __restrict__ b2) {
  int r = blockIdx.x, t = threadIdx.x;
  int c = t * 4;
  __shared__ float red[8];
  int lane = t & 63, w = t >> 6;
  us4 xb = *(const us4*)&Xb[(size_t)r * Dn + c];
  us4 yb = *(const us4*)&Y[(size_t)r * Dn + c];
  f4 v;
  v[0] = bf2f(xb[0]) + bf2f(yb[0]); v[1] = bf2f(xb[1]) + bf2f(yb[1]);
  v[2] = bf2f(xb[2]) + bf2f(yb[2]); v[3] = bf2f(xb[3]) + bf2f(yb[3]);
  float sum = v[0] + v[1] + v[2] + v[3];
  float sq = v[0]*v[0] + v[1]*v[1] + v[2]*v[2] + v[3]*v[3];
  for (int off = 32; off; off >>= 1) {
    sum += __shfl_down(sum, off, 64);
    sq  += __shfl_down(sq,  off, 64);
  }
  if (!lane) { red[w] = sum; red[2 + w] = sq; }
  __syncthreads();
  sum = red[0] + red[1]; sq = red[2] + red[3];
  float mu = sum * (1.0f / Dn);
  float var = sq * (1.0f / Dn) - mu * mu;
  float rstd = rsqrtf(fmaxf(var, 0.0f) + 1e-5f);
  f4 g1v = *(const f4*)&g1[c];
  f4 b1v = *(const f4*)&b1[c];
  f4 o1 = (v - mu) * rstd * g1v + b1v;
  f4 ca = *(const f4*)&CA[(size_t)(r >> 7) * Dn + c];
  f4 v2 = o1 + ca;
  float sum2 = v2[0] + v2[1] + v2[2] + v2[3];
  float sq2 = v2[0]*v2[0] + v2[1]*v2[1] + v2[2]*v2[2] + v2[3]*v2[3];
  for (int off = 32; off; off >>= 1) {
    sum2 += __shfl_down(sum2, off, 64);
    sq2  += __shfl_down(sq2,  off, 64);
  }
  if (!lane) { red[4 + w] = sum2; red[6 + w] = sq2; }
  __syncthreads();
  sum2 = red[4] + red[5]; sq2 = red[6] + red[7];
  float mu2 = sum2 * (1.0f / Dn);
  float var2 = sq2 * (1.0f / Dn) - mu2 * mu2;
  float rstd2 = rsqrtf(fmaxf(var2, 0.0f) + 1e-5f);
  f4 g2v = *(const f4*)&g2[c];
  f4 b2v = *(const f4*)&b2[c];
  f4 o2 = (v2 - mu2) * rstd2 * g2v + b2v;
  us4 ob = { f2bf(o2[0]), f2bf(o2[1]), f2bf(o2[2]), f2bf(o2[3]) };
  *(us4*)&Xb[(size_t)r * Dn + c] = ob;
}

// ---------------- MFMA causal attention (R9-R15 passing kernel, unchanged) ---
__global__ __launch_bounds__(256, 1)
void k_attn_m(const u16* __restrict__ QKV, u16* __restrict__ Ob) {
  constexpr int QS = 0;
  constexpr int KS = 9216;
  constexpr int SFB = 36864;
  constexpr int VTB = 36864 + 66048;
  constexpr int MXB = VTB + 17408;
  constexpr int LXB = MXB + 1024;
  __shared__ __align__(16) char smem[LXB + 1024];
  u16* U = (u16*)smem;
  float* Sf = (float*)(smem + SFB);
  u16* Vt = (u16*)(smem + VTB);
  float* Mx = (float*)(smem + MXB);
  float* Lx = (float*)(smem + LXB);

  int bh = blockIdx.x, b = bh >> 3, h = bh & 7;
  int tid = threadIdx.x, lane = tid & 63, wid = tid >> 6;
  int r = tid & 127, half = tid >> 7;

  {
    const u16* qk = QKV + (size_t)(b * 128 + r) * 1536 + (half ? 512 : 0) + h * 64;
    u16* dst = U + (half ? KS : QS) + r * 72;
    #pragma unroll
    for (int i = 0; i < 64; i += 8)
      *(short8*)(dst + i) = *(const short8*)(qk + i);
    const u16* vsrc = QKV + (size_t)(b * 128 + r) * 1536 + 1024 + h * 64 + half * 32;
    #pragma unroll
    for (int i = 0; i < 32; i += 8) {
      short8 v = *(const short8*)(vsrc + i);
      #pragma unroll
      for (int j = 0; j < 8; j++)
        Vt[(half * 32 + i + j) * 136 + r] = (u16)v[j];
    }
  }
  __syncthreads();

  int qb = wid * 32;
  int fr = lane & 15, qk8 = (lane >> 4) * 8, qrl = (lane >> 4) * 4;
  f32x4 sacc[2][8] = {};
  #pragma unroll
  for (int s = 0; s < 2; s++) {
    short8 av[2], bv[8];
    #pragma unroll
    for (int mi = 0; mi < 2; mi++)
      av[mi] = *(const short8*)(U + QS + (qb + mi * 16 + fr) * 72 + s * 32 + qk8);
    #pragma unroll
    for (int nj = 0; nj < 8; nj++)
      bv[nj] = *(const short8*)(U + KS + (nj * 16 + fr) * 72 + s * 32 + qk8);
    #pragma unroll
    for (int mi = 0; mi < 2; mi++)
      #pragma unroll
      for (int nj = 0; nj < 8; nj++)
        sacc[mi][nj] = __builtin_amdgcn_mfma_f32_16x16x32_bf16(
            av[mi], bv[nj], sacc[mi][nj], 0, 0, 0);
  }
  #pragma unroll
  for (int mi = 0; mi < 2; mi++)
    #pragma unroll
    for (int nj = 0; nj < 8; nj++)
      #pragma unroll
      for (int g = 0; g < 4; g++) {
        int q = qb + mi * 16 + qrl + g;
        int k = nj * 16 + fr;
        Sf[q * 129 + k] = (k <= q) ? sacc[mi][nj][g] * 0.125f : -1e30f;
      }
  __syncthreads();

  int kr = half * 64;
  float m = -1e30f;
  for (int k = 0; k < 64; k++) m = fmaxf(m, Sf[r * 129 + kr + k]);
  Mx[half * 128 + r] = m;
  __syncthreads();
  float mm = fmaxf(Mx[r], Mx[128 + r]);
  float l = 0.0f;
  for (int k = 0; k < 64; k++) {
    float p = __expf(Sf[r * 129 + kr + k] - mm);
    Sf[r * 129 + kr + k] = p;
    l += p;
  }
  Lx[half * 128 + r] = l;
  __syncthreads();
  float linv = 1.0f / (Lx[r] + Lx[128 + r]);
  #pragma unroll
  for (int kc = 0; kc < 8; kc++) {
    short8 pv;
    #pragma unroll
    for (int j = 0; j < 8; j++)
      pv[j] = (short)f2bf(Sf[r * 129 + kr + kc * 8 + j] * linv);
    *(short8*)(U + r * 136 + kr + kc * 8) = pv;
  }
  __syncthreads();

  f32x4 oacc[2][4] = {};
  #pragma unroll
  for (int ks = 0; ks < 4; ks++) {
    short8 av[2], bv[4];
    #pragma unroll
    for (int mi = 0; mi < 2; mi++)
      av[mi] = *(const short8*)(U + (qb + mi * 16 + fr) * 136 + ks * 32 + qk8);
    #pragma unroll
    for (int nj = 0; nj < 4; nj++)
      bv[nj] = *(const short8*)(Vt + (nj * 16 + fr) * 136 + ks * 32 + qk8);
    #pragma unroll
    for (int mi = 0; mi < 2; mi++)
      #pragma unroll
      for (int nj = 0; nj < 4; nj++)
        oacc[mi][nj] = __builtin_amdgcn_mfma_f32_16x16x32_bf16(
            av[mi], bv[nj], oacc[mi][nj], 0, 0, 0);
  }
  #pragma unroll
  for (int mi = 0; mi < 2; mi++)
    #pragma unroll
    for (int nj = 0; nj < 4; nj++)
      #pragma unroll
      for (int g = 0; g < 4; g++) {
        int q = qb + mi * 16 + qrl + g;
        int d = nj * 16 + fr;
        Ob[(size_t)(b * 128 + q) * 512 + h * 64 + d] = f2bf(oacc[mi][nj][g]);
      }
}

// ---------------- layer GEMM: BMTxBNT tile, BK=64, proven 2-phase protocol ---
// Generalized with BMT (tile-geometry change only; sync structure identical).
// BMT=64 -> grid doubles for N=512 GEMMs: 2 blocks/CU instead of 1.
// EPI 0: f32 +bias.  EPI 1: relu(+bias)->bf16.  EPI 2: +bias->bf16.
template <int EPI, int BMT, int BNT>
__global__ __launch_bounds__(256, 2)
void k_gemm_bt(const u16* __restrict__ A, const u16* __restrict__ Bw,
               const float* __restrict__ bias, void* __restrict__ Cout,
               int gm, int N, int K, int ldc) {
  constexpr int MREP = BMT / 32;
  constexpr int NREP = BNT / 32;
  constexpr int ASTRIDE = BMT * 64;
  constexpr int BSTRIDE = BNT * 64;
  constexpr int TSTRIDE = BNT + 4;
  constexpr int NLA = BMT / 32;
  constexpr int NLB = BNT / 32;
  __shared__ __align__(16) char smem[(ASTRIDE + BSTRIDE) * 4];
  u16* As = (u16*)smem;
  u16* Bs = (u16*)(smem + ASTRIDE * 4);
  float* Ts = (float*)smem;

  int lin = blockIdx.x;
  int bm = lin % gm, bn = lin / gm;
  int tid = threadIdx.x, lane = tid & 63, wid = tid >> 6;
  int wr = wid >> 1, wc = wid & 1;
  int fr = lane & 15, q = lane >> 4;
  f32x4 acc[MREP][NREP] = {};

  auto stage = [&](int it) {
    int buf = it & 1;
    #pragma unroll
    for (int l = 0; l < NLA; l++) {
      int c = tid + l * 256;
      int row = c >> 3;
      int kcg = (c & 7) ^ (row & 7);
      GLD(A + (size_t)(bm * BMT + row) * K + it * 64 + kcg * 8,
          (char*)(As + buf * ASTRIDE) + c * 16);
    }
    #pragma unroll
    for (int l = 0; l < NLB; l++) {
      int c = tid + l * 256;
      int row = c >> 3;
      int kcg = (c & 7) ^ (row & 7);
      GLD(Bw + (size_t)(bn * BNT + row) * K + it * 64 + kcg * 8,
          (char*)(Bs + buf * BSTRIDE) + c * 16);
    }
  };

  int nt = K >> 6;
  stage(0);
  for (int it = 0; it < nt; ++it) {
    int cur = it & 1;
    if (it + 1 < nt) {
      stage(it + 1);
      if constexpr (NLA + NLB == 8)      asm volatile("s_waitcnt vmcnt(8)" ::: "memory");
      else if constexpr (NLA + NLB == 6) asm volatile("s_waitcnt vmcnt(6)" ::: "memory");
      else                               asm volatile("s_waitcnt vmcnt(4)" ::: "memory");
    } else {
      asm volatile("s_waitcnt vmcnt(0)" ::: "memory");
    }
    __builtin_amdgcn_sched_barrier(0);
    __builtin_amdgcn_s_barrier();
    __builtin_amdgcn_sched_barrier(0);
    short8 av[2][MREP], bv[2][NREP];
    #pragma unroll
    for (int s = 0; s < 2; s++) {
      #pragma unroll
      for (int mi = 0; mi < MREP; mi++) {
        int row = wr * (BMT / 2) + mi * 16 + fr;
        int phys = (s * 4 + q) ^ (row & 7);
        av[s][mi] = *(const short8*)&As[cur * ASTRIDE + row * 64 + phys * 8];
      }
      #pragma unroll
      for (int nj = 0; nj < NREP; nj++) {
        int row = wc * (BNT / 2) + nj * 16 + fr;
        int phys = (s * 4 + q) ^ (row & 7);
        bv[s][nj] = *(const short8*)&Bs[cur * BSTRIDE + row * 64 + phys * 8];
      }
    }
    #pragma unroll
    for (int s = 0; s < 2; s++)
      #pragma unroll
      for (int mi = 0; mi < MREP; mi++)
        #pragma unroll
        for (int nj = 0; nj < NREP; nj++)
          acc[mi][nj] = __builtin_amdgcn_mfma_f32_16x16x32_bf16(
              av[s][mi], bv[s][nj], acc[mi][nj], 0, 0, 0);
    asm volatile("s_waitcnt lgkmcnt(0)" ::: "memory");
    __builtin_amdgcn_sched_barrier(0);
    __builtin_amdgcn_s_barrier();
    __builtin_amdgcn_sched_barrier(0);
  }

  float bb[NREP];
  #pragma unroll
  for (int nj = 0; nj < NREP; nj++) {
    int cg = bn * BNT + wc * (BNT / 2) + nj * 16 + fr;
    bb[nj] = (cg < N) ? bias[cg] : 0.0f;
  }
  int rl0 = (lane >> 4) * 4;
  #pragma unroll
  for (int mi = 0; mi < MREP; mi++) {
    #pragma unroll
    for (int nj = 0; nj < NREP; nj++) {
      int colL = wc * (BNT / 2) + nj * 16 + fr;
      #pragma unroll
      for (int r = 0; r < 4; r++)
        Ts[(wr * 16 + rl0 + r) * TSTRIDE + colL] = acc[mi][nj][r] + bb[nj];
    }
    __syncthreads();
    constexpr int ITERS = (32 * BNT) / 256;
    #pragma unroll
    for (int i = 0; i < ITERS; i++) {
      int flat = i * 256 + tid;
      int rowf = flat / BNT, col = flat % BNT;
      float v = Ts[rowf * TSTRIDE + col];
      int row_g = bm * BMT + (rowf >> 4) * (BMT / 2) + mi * 16 + (rowf & 15);
      int col_g = bn * BNT + col;
      size_t off = (size_t)row_g * ldc + col_g;
      if (EPI == 0) {
        if (col_g < N) ((float*)Cout)[off] = v;
      } else if (EPI == 1) {
        ((u16*)Cout)[off] = f2bf(fmaxf(v, 0.0f));
      } else {
        ((u16*)Cout)[off] = f2bf(v);
      }
    }
    if (mi < MREP - 1) __syncthreads();
  }
}

// ---------------- vocab GEMM: 256x256 tile, BK=64, 8 waves (R13-exact) -------
__global__ __launch_bounds__(512, 2)
void k_gemm_v256(const u16* __restrict__ A, const u16* __restrict__ Bw,
                 const float* __restrict__ bias, float* __restrict__ Cout,
                 int gm, int N, int K, int ldc) {
  constexpr int ASTRIDE = 256 * 64;
  constexpr int BSTRIDE = 256 * 64;
  constexpr int TSTRIDE = 256 + 4;
  __shared__ __align__(16) char smem[(ASTRIDE + BSTRIDE) * 4];   // 128 KB
  u16* As = (u16*)smem;
  u16* Bs = (u16*)(smem + ASTRIDE * 4);
  float* Ts = (float*)smem;

  int lin = blockIdx.x;
  int bm = lin % gm, bn = lin / gm;
  int tid = threadIdx.x, lane = tid & 63, wid = tid >> 6;
  int wr = wid >> 2, wc = wid & 3;
  int fr = lane & 15, q = lane >> 4;
  f32x4 acc[8][4] = {};

  auto stage = [&](int it) {
    int buf = it & 1;
    #pragma unroll
    for (int l = 0; l < 4; l++) {
      int c = tid + l * 512;
      int row = c >> 3;
      int kcg = (c & 7) ^ (row & 7);
      GLD(A + (size_t)(bm * 256 + row) * K + it * 64 + kcg * 8,
          (char*)(As + buf * ASTRIDE) + c * 16);
    }
    #pragma unroll
    for (int l = 0; l < 4; l++) {
      int c = tid + l * 512;
      int row = c >> 3;
      int rowg = bn * 256 + row;
      if (rowg > VPAD - 1) rowg = VPAD - 1;
      int kcg = (c & 7) ^ (row & 7);
      GLD(Bw + (size_t)rowg * K + it * 64 + kcg * 8,
          (char*)(Bs + buf * BSTRIDE) + c * 16);
    }
  };

  int nt = K >> 6;
  stage(0);
  for (int it = 0; it < nt; ++it) {
    int cur = it & 1;
    if (it + 1 < nt) {
      stage(it + 1);
      asm volatile("s_waitcnt vmcnt(8)" ::: "memory");
    } else {
      asm volatile("s_waitcnt vmcnt(0)" ::: "memory");
    }
    __builtin_amdgcn_sched_barrier(0);
    __builtin_amdgcn_s_barrier();
    __builtin_amdgcn_sched_barrier(0);
    #pragma unroll
    for (int s = 0; s < 2; s++) {
      short8 av[8], bv[4];
      #pragma unroll
      for (int mi = 0; mi < 8; mi++) {
        int row = wr * 128 + mi * 16 + fr;
        int phys = (s * 4 + q) ^ (row & 7);
        av[mi] = *(const short8*)&As[cur * ASTRIDE + row * 64 + phys * 8];
      }
      #pragma unroll
      for (int nj = 0; nj < 4; nj++) {
        int row = wc * 64 + nj * 16 + fr;
        int phys = (s * 4 + q) ^ (row & 7);
        bv[nj] = *(const short8*)&Bs[cur * BSTRIDE + row * 64 + phys * 8];
      }
      #pragma unroll
      for (int mi = 0; mi < 8; mi++)
        #pragma unroll
        for (int nj = 0; nj < 4; nj++)
          acc[mi][nj] = __builtin_amdgcn_mfma_f32_16x16x32_bf16(
              av[mi], bv[nj], acc[mi][nj], 0, 0, 0);
    }
    asm volatile("s_waitcnt lgkmcnt(0)" ::: "memory");
    __builtin_amdgcn_sched_barrier(0);
    __builtin_amdgcn_s_barrier();
    __builtin_amdgcn_sched_barrier(0);
  }

  float bb[4];
  #pragma unroll
  for (int nj = 0; nj < 4; nj++) {
    int cg = bn * 256 + wc * 64 + nj * 16 + fr;
    bb[nj] = (cg < N) ? bias[cg] : 0.0f;
  }
  int rl0 = (lane >> 4) * 4;
  #pragma unroll
  for (int mi = 0; mi < 8; mi++) {
    #pragma unroll
    for (int nj = 0; nj < 4; nj++) {
      int colL = wc * 64 + nj * 16 + fr;
      #pragma unroll
      for (int r = 0; r < 4; r++)
        Ts[(wr * 16 + rl0 + r) * TSTRIDE + colL] = acc[mi][nj][r] + bb[nj];
    }
    __syncthreads();
    #pragma unroll
    for (int i = 0; i < 16; i++) {
      int flat = i * 512 + tid;
      int rowf = flat >> 8, col = flat & 255;
      float v = Ts[rowf * TSTRIDE + col];
      int row_g = bm * 256 + (rowf >> 4) * 128 + mi * 16 + (rowf & 15);
      int col_g = bn * 256 + col;
      if (col_g < N)
        Cout[(size_t)row_g * ldc + col_g] = v;
    }
    if (mi < 7) __syncthreads();
  }
}

// =============================================================================
extern "C" void kernel_launch(void* const* d_in, const int* in_sizes, int n_in,
                              void* d_out, int out_size, void* d_ws, size_t ws_size,
                              hipStream_t stream) {
  const float* z        = (const float*)d_in[0];
  const int*   ids      = (const int*)d_in[1];
  const float* tok      = (const float*)d_in[2];
  const float* pos      = (const float*)d_in[3];
  const float* lp_w     = (const float*)d_in[4];
  const float* lp_b     = (const float*)d_in[5];
  const float* lp_g     = (const float*)d_in[6];
  const float* lp_be    = (const float*)d_in[7];
  const float* sa_qkv_w = (const float*)d_in[8];
  const float* sa_qkv_b = (const float*)d_in[9];
  const float* sa_out_w = (const float*)d_in[10];
  const float* sa_out_b = (const float*)d_in[11];
  const float* ca_qkv_w = (const float*)d_in[12];
  const float* ca_qkv_b = (const float*)d_in[13];
  const float* ca_out_w = (const float*)d_in[14];
  const float* ca_out_b = (const float*)d_in[15];
  const float* ln1_g    = (const float*)d_in[16];
  const float* ln1_b    = (const float*)d_in[17];
  const float* ln2_g    = (const float*)d_in[18];
  const float* ln2_b    = (const float*)d_in[19];
  const float* ln3_g    = (const float*)d_in[20];
  const float* ln3_b    = (const float*)d_in[21];
  const float* ff1_w    = (const float*)d_in[22];
  const float* ff1_b    = (const float*)d_in[23];
  const float* ff2_w    = (const float*)d_in[24];
  const float* ff2_b    = (const float*)d_in[25];
  const float* op_w     = (const float*)d_in[26];
  const float* op_b     = (const float*)d_in[27];

  char* ws = (char*)d_ws;
  u16*   Yb     = (u16*)(ws + 8388608);       // 4096x512 bf16
  u16*   QKVb   = (u16*)(ws + 16777216);      // 4096x1536 bf16
  u16*   Xb     = (u16*)(ws + 29360128);      // 4096x512 bf16 (residual stream)
  u16*   Ob     = (u16*)(ws + 33554432);      // 4096x512 bf16
  u16*   H1b    = (u16*)(ws + 37748736);      // 4096x2048 bf16
  float* ca_add = (float*)(ws + 54657024);    // 4x32x512 f32
  u16*   Wa     = (u16*)(ws + 55050240);      // weight arena bf16 (contiguous)

  u16* Wqkv = Wa;                              // 4 x 1536x512
  u16* Wout = Wa + 3145728;                    // 4 x 512x512
  u16* Wff1 = Wa + 4194304;                    // 4 x 2048x512
  u16* Wff2 = Wa + 8388608;                    // 4 x 512x2048
  u16* Wop  = Wa + 12582912;                   // 50304x512 (zero-padded tail)

  k_ca<<<4 * Bn, 256, 0, stream>>>(z, lp_w, lp_b, lp_g, lp_be,
                                   ca_qkv_w, ca_qkv_b, ca_out_w, ca_out_b, ca_add);
  k_embed<<<Bn * Ln, 128, 0, stream>>>(ids, tok, pos, Xb);
  k_cvt_all<<<2048, 256, 0, stream>>>(sa_qkv_w, sa_out_w, ff1_w, ff2_w, op_w,
                                      (us4*)Wa);

  const int M = Bn * Ln;  // 4096
  for (int i = 0; i < 4; i++) {
    k_gemm_bt<2, 128, 128><<<32 * 12, 256, 0, stream>>>(
        Xb, Wqkv + (size_t)i * 1536 * Dn, sa_qkv_b + i * 1536, QKVb, 32, 1536, Dn, 1536);
    k_attn_m<<<Bn * Hn, 256, 0, stream>>>(QKVb, Ob);
    k_gemm_bt<2, 64, 64><<<64 * 8, 256, 0, stream>>>(
        Ob, Wout + (size_t)i * Dn * Dn, sa_out_b + i * Dn, Yb, 64, Dn, Dn, Dn);
    k_add_ln12<<<M, 128, 0, stream>>>(Xb, Yb, ca_add + (size_t)i * Bn * Dn,
                                      ln1_g + i * Dn, ln1_b + i * Dn,
                                      ln2_g + i * Dn, ln2_b + i * Dn);
    k_gemm_bt<1, 128, 128><<<32 * 16, 256, 0, stream>>>(
        Xb, Wff1 + (size_t)i * DFn * Dn, ff1_b + i * DFn, H1b, 32, DFn, Dn, DFn);
    k_gemm_bt<2, 64, 64><<<64 * 8, 256, 0, stream>>>(
        H1b, Wff2 + (size_t)i * Dn * DFn, ff2_b + i * Dn, Yb, 64, Dn, DFn, Dn);
    k_add_ln<<<M, 128, 0, stream>>>(Xb, Yb, ln3_g + i * Dn, ln3_b + i * Dn);
  }

  // final vocab projection -> d_out (f32): 256x256 tiles, BK=64, 16 x 197 grid
  k_gemm_v256<<<16 * 197, 512, 0, stream>>>(
      Xb, Wop, op_b, (float*)d_out, 16, Vn, Dn, Vn);
}